// Round 10
// baseline (53.543 us; speedup 1.0000x reference)
//
#include <hip/hip_runtime.h>
#include <math.h>

// out[b,i,h,w] = Ar[b,h,i]*cos(2*pi*i*w/128)/128 - Ai[b,h,i]*sin(2*pi*i*w/128)/128
// A = row-DFT of x (fft2 + ifft over H == fft over W). mask unused.
// x real => out[b,128-i] == out[b,i] EXACTLY: compute i=0..64, store mirrors.
//
// v9 = v6 (best: zero LDS / zero barriers / register x / sequential
// single-stream plane stores / pipelined DFT) with ONE change:
// nontemporal stores. The 268 MB streaming output write-allocates through
// L2/L3 at exactly L3 capacity (268 vs 256 MB); nt (evict-first) removes
// the thrash. Clean A/B vs round 6's 49.9 us.
// Grid: 1024 = 32 b x 32 groups; group g: planes {2g,2g+1} (+64 for g=0).

typedef float f32x4 __attribute__((ext_vector_type(4)));

__device__ __forceinline__ void dft_plane(const float* xs, int i, int half,
                                          float& arO, float& aiO) {
    // rotation step e^{-I*2*pi*i/128}
    float sstep, cstep;
    sincospif((float)i * (1.0f / 64.0f), &sstep, &cstep);
    const float dc = cstep, ds = -sstep;
    float ar = 0.0f, ai = 0.0f;
#pragma unroll
    for (int ch = 0; ch < 2; ++ch) {
        const int u0 = half * 64 + ch * 32;
        const int a0 = (i * u0) & 127;           // exact mod-128 phase re-init
        float s0, c0;
        sincospif((float)a0 * (1.0f / 64.0f), &s0, &c0);
        float cr = c0, ci = -s0;                 // e^{-I*theta(u0)}
#pragma unroll
        for (int j2 = 0; j2 < 32; ++j2) {
            const float xv = xs[ch * 32 + j2];
            ar = fmaf(xv, cr, ar);
            ai = fmaf(xv, ci, ai);
            const float ncr = fmaf(cr, dc, -ci * ds);
            ci = fmaf(cr, ds, ci * dc);
            cr = ncr;
        }
    }
    ar += __shfl_xor(ar, 1);                     // pair combine: both lanes hold sum
    ai += __shfl_xor(ai, 1);
    arO = ar * (1.0f / 128.0f);
    aiO = ai * (1.0f / 128.0f);
}

__global__ __launch_bounds__(256) void kspace_v9(const float* __restrict__ x,
                                                 float* __restrict__ out) {
    const int blk  = blockIdx.x;       // 0..1023
    const int b    = blk >> 5;
    const int g    = blk & 31;
    const int t    = threadIdx.x;
    const int wv   = t >> 6;           // wave 0..3 -> DFT+store rows [32wv,32wv+32)
    const int lane = t & 63;
    const int h    = wv * 32 + (lane >> 1);   // this thread's DFT row
    const int half = lane & 1;                // which 64-sample half

    // ---- my half-row (64 floats, 256 B contiguous) into registers ----
    const float* xp = x + ((size_t)b * 128 + h) * 128 + half * 64;
    float xs[64];
#pragma unroll
    for (int j = 0; j < 16; ++j) {
        const f32x4 v = ((const f32x4*)xp)[j];
        xs[4 * j + 0] = v.x;
        xs[4 * j + 1] = v.y;
        xs[4 * j + 2] = v.z;
        xs[4 * j + 3] = v.w;
    }

    const int nP = (g == 0) ? 3 : 2;   // planes: {2g, 2g+1} (+ 64 for g=0)

    // peel DFT of first plane
    float arC, aiC;
    dft_plane(xs, 2 * g, half, arC, aiC);

#pragma unroll 1
    for (int p = 0; p < nP; ++p) {
        const int i = (p < 2) ? (2 * g + p) : 64;

        // per-lane trig for its 4 fixed w-columns: w = 4*(lane&31)+c
        const int wbase = (lane & 31) * 4;
        float cwv[4], swv[4];
#pragma unroll
        for (int c = 0; c < 4; ++c) {
            const int k = (i * (wbase + c)) & 127;
            sincospif((float)k * (1.0f / 64.0f), &swv[c], &cwv[c]);
        }

        const int npass = (i == 0 || i == 64) ? 1 : 2;
#pragma unroll 1
        for (int pass = 0; pass < npass; ++pass) {
            const int pl = pass ? (128 - i) : i;
            f32x4* const o = (f32x4*)out + (size_t)(b * 128 + pl) * 4096;
#pragma unroll
            for (int j = 0; j < 16; ++j) {
                // wave wv writes f32x4 q = wv*1024 + 64j + lane (1KB/instr, coalesced)
                // row hh = q>>5 = 32wv + 2j + (lane>>5); A owner lane = 2*(2j+(lane>>5))
                const int src = 4 * j + 2 * (lane >> 5);
                const float a  = __shfl(arC, src);
                const float bb = __shfl(aiC, src);
                f32x4 v;
                v.x = fmaf(a, cwv[0], -bb * swv[0]);
                v.y = fmaf(a, cwv[1], -bb * swv[1]);
                v.z = fmaf(a, cwv[2], -bb * swv[2]);
                v.w = fmaf(a, cwv[3], -bb * swv[3]);
                __builtin_nontemporal_store(v, &o[wv * 1024 + j * 64 + lane]);
            }
        }

        // DFT of next plane, overlapped with the in-flight stores above
        if (p + 1 < nP) {
            const int inext = (p + 1 < 2) ? (2 * g + p + 1) : 64;
            float arN, aiN;
            dft_plane(xs, inext, half, arN, aiN);
            arC = arN;
            aiC = aiN;
        }
    }
}

extern "C" void kernel_launch(void* const* d_in, const int* in_sizes, int n_in,
                              void* d_out, int out_size, void* d_ws, size_t ws_size,
                              hipStream_t stream) {
    const float* x = (const float*)d_in[0];   // (32,1,128,128) f32; mask unused
    float* out = (float*)d_out;               // (32,128,128,128) f32
    kspace_v9<<<dim3(1024), dim3(256), 0, stream>>>(x, out);
}

// Round 11
// 49.615 us; speedup vs baseline: 1.0792x; 1.0792x over previous
//
#include <hip/hip_runtime.h>
#include <math.h>

// out[b,i,h,w] = Ar[b,h,i]*cos(2*pi*i*w/128)/128 - Ai[b,h,i]*sin(2*pi*i*w/128)/128
// A = row-DFT of x (fft2 + ifft over H == fft over W). mask unused.
// x real => out[b,128-i] == out[b,i] EXACTLY: compute i=0..64, store mirrors.
//
// FINAL (= round-6 v6, the measured best at 49.9 us): zero LDS, zero
// barriers. x half-row in registers; DFT via in-register complex rotation
// (exact mod-128 phase re-anchor every 32 steps); A handed to the store loop
// by 2 __shfl's per iter; planes software-pipelined (stores of plane p
// overlap DFT of p+1; no syncthreads -> store queue never drained). Plain
// coalesced 1KB-per-instruction stores (NT stores measured -3.6 us: refuted).
// Grid: 1024 = 32 b x 32 groups; group g: planes {2g,2g+1} (+64 for g=0).
//
// Theory matrix over rounds 2-9 (all refuted vs this structure):
//   LDS+barrier staging (v2 50.1), broadcast-LDS DFT (v5 51.4),
//   fine-grained DFT/store interleave (v7 51.2), linear write map +
//   bijective XCD swizzle (v8 52.9), nontemporal stores (v9 53.5).
// Residual ~12 us over the 38 us fill-BW floor = fixed dispatch cost
// (launch/replay ~5 us, L2 dirty tail ~4.5 us, cold read ramp ~1-2 us).

typedef float f32x4 __attribute__((ext_vector_type(4)));

__device__ __forceinline__ void dft_plane(const float* xs, int i, int half,
                                          float& arO, float& aiO) {
    // rotation step e^{-I*2*pi*i/128}
    float sstep, cstep;
    sincospif((float)i * (1.0f / 64.0f), &sstep, &cstep);
    const float dc = cstep, ds = -sstep;
    float ar = 0.0f, ai = 0.0f;
#pragma unroll
    for (int ch = 0; ch < 2; ++ch) {
        const int u0 = half * 64 + ch * 32;
        const int a0 = (i * u0) & 127;           // exact mod-128 phase re-init
        float s0, c0;
        sincospif((float)a0 * (1.0f / 64.0f), &s0, &c0);
        float cr = c0, ci = -s0;                 // e^{-I*theta(u0)}
#pragma unroll
        for (int j2 = 0; j2 < 32; ++j2) {
            const float xv = xs[ch * 32 + j2];
            ar = fmaf(xv, cr, ar);
            ai = fmaf(xv, ci, ai);
            const float ncr = fmaf(cr, dc, -ci * ds);
            ci = fmaf(cr, ds, ci * dc);
            cr = ncr;
        }
    }
    ar += __shfl_xor(ar, 1);                     // pair combine: both lanes hold sum
    ai += __shfl_xor(ai, 1);
    arO = ar * (1.0f / 128.0f);
    aiO = ai * (1.0f / 128.0f);
}

__global__ __launch_bounds__(256) void kspace_v6(const float* __restrict__ x,
                                                 float* __restrict__ out) {
    const int blk  = blockIdx.x;       // 0..1023
    const int b    = blk >> 5;
    const int g    = blk & 31;
    const int t    = threadIdx.x;
    const int wv   = t >> 6;           // wave 0..3 -> DFT+store rows [32wv,32wv+32)
    const int lane = t & 63;
    const int h    = wv * 32 + (lane >> 1);   // this thread's DFT row
    const int half = lane & 1;                // which 64-sample half

    // ---- my half-row (64 floats, 256 B contiguous) into registers ----
    const float* xp = x + ((size_t)b * 128 + h) * 128 + half * 64;
    float xs[64];
#pragma unroll
    for (int j = 0; j < 16; ++j) {
        const f32x4 v = ((const f32x4*)xp)[j];
        xs[4 * j + 0] = v.x;
        xs[4 * j + 1] = v.y;
        xs[4 * j + 2] = v.z;
        xs[4 * j + 3] = v.w;
    }

    const int nP = (g == 0) ? 3 : 2;   // planes: {2g, 2g+1} (+ 64 for g=0)

    // peel DFT of first plane
    float arC, aiC;
    dft_plane(xs, 2 * g, half, arC, aiC);

#pragma unroll 1
    for (int p = 0; p < nP; ++p) {
        const int i = (p < 2) ? (2 * g + p) : 64;

        // per-lane trig for its 4 fixed w-columns: w = 4*(lane&31)+c
        const int wbase = (lane & 31) * 4;
        float cwv[4], swv[4];
#pragma unroll
        for (int c = 0; c < 4; ++c) {
            const int k = (i * (wbase + c)) & 127;
            sincospif((float)k * (1.0f / 64.0f), &swv[c], &cwv[c]);
        }

        const int npass = (i == 0 || i == 64) ? 1 : 2;
#pragma unroll 1
        for (int pass = 0; pass < npass; ++pass) {
            const int pl = pass ? (128 - i) : i;
            f32x4* const o = (f32x4*)out + (size_t)(b * 128 + pl) * 4096;
#pragma unroll
            for (int j = 0; j < 16; ++j) {
                // wave wv writes f32x4 q = wv*1024 + 64j + lane (1KB/instr, coalesced)
                // row hh = q>>5 = 32wv + 2j + (lane>>5); A owner lane = 4j + 2*(lane>>5)
                const int src = 4 * j + 2 * (lane >> 5);
                const float a  = __shfl(arC, src);
                const float bb = __shfl(aiC, src);
                f32x4 v;
                v.x = fmaf(a, cwv[0], -bb * swv[0]);
                v.y = fmaf(a, cwv[1], -bb * swv[1]);
                v.z = fmaf(a, cwv[2], -bb * swv[2]);
                v.w = fmaf(a, cwv[3], -bb * swv[3]);
                o[wv * 1024 + j * 64 + lane] = v;
            }
        }

        // DFT of next plane, overlapped with the in-flight stores above
        if (p + 1 < nP) {
            const int inext = (p + 1 < 2) ? (2 * g + p + 1) : 64;
            float arN, aiN;
            dft_plane(xs, inext, half, arN, aiN);
            arC = arN;
            aiC = aiN;
        }
    }
}

extern "C" void kernel_launch(void* const* d_in, const int* in_sizes, int n_in,
                              void* d_out, int out_size, void* d_ws, size_t ws_size,
                              hipStream_t stream) {
    const float* x = (const float*)d_in[0];   // (32,1,128,128) f32; mask unused
    float* out = (float*)d_out;               // (32,128,128,128) f32
    kspace_v6<<<dim3(1024), dim3(256), 0, stream>>>(x, out);
}